// Round 2
// baseline (698.866 us; speedup 1.0000x reference)
//
#include <hip/hip_runtime.h>
#include <hip/hip_bf16.h>

#define NF 40960
#define MD 256
#define BATCH 2048
#define NCHUNK 4
#define CHUNK (NF / NCHUNK)   // 10240 floats per chunk
#define CAPC 32               // max nonzeros per chunk (mean 8, +8.5 sigma)

#define SCAN_BLOCKS (2 * BATCH * NCHUNK)          // 16384
#define TRANS_BLOCKS ((NF / 64) * (MD / 64))      // 2560

__device__ __forceinline__ float clip01(float v) {
    return fminf(fmaxf(v, 0.0f), 1.0f);
}

// ---------------------------------------------------------------------------
// Kernel 1: fused sparse-scan (compact nonzero feature indices per
// (pos,color,chunk)) + ft_w transpose [256,40960] -> ftT [40960,256].
// Scan blocks write their own count slot, so no ws zero-init is needed.
// ---------------------------------------------------------------------------
__global__ __launch_bounds__(256) void scan_transpose(
    const float* __restrict__ wf, const float* __restrict__ bfeat,
    const float* __restrict__ ft_w,
    float* __restrict__ ftT, int* __restrict__ g_cnt, int* __restrict__ g_idx)
{
    __shared__ float tile[64][65];   // transpose path; 16.6 KB
    __shared__ int s_cnt;
    __shared__ int s_idx[CAPC];

    const int b = blockIdx.x;
    const int t = threadIdx.x;

    if (b < SCAN_BLOCKS) {
        const int chunk = b & 3;
        const int pc    = b >> 2;        // pos*2 + color
        const int color = pc & 1;
        const int pos   = pc >> 1;

        if (t == 0) s_cnt = 0;
        __syncthreads();

        const float* src = (color ? bfeat : wf) + (size_t)pos * NF + chunk * CHUNK;
        const float4* p4 = (const float4*)src;

        // issue ALL loads before any use -> max memory-level parallelism
        float4 v[10];
        #pragma unroll
        for (int k = 0; k < 10; ++k) v[k] = p4[t + 256 * k];

        #pragma unroll
        for (int k = 0; k < 10; ++k) {
            float4 a = v[k];
            if (a.x + a.y + a.z + a.w != 0.0f) {          // values are exactly 0/1
                const int e = chunk * CHUNK + 4 * (t + 256 * k);
                if (a.x != 0.0f) { int q = atomicAdd(&s_cnt, 1); if (q < CAPC) s_idx[q] = e;     }
                if (a.y != 0.0f) { int q = atomicAdd(&s_cnt, 1); if (q < CAPC) s_idx[q] = e + 1; }
                if (a.z != 0.0f) { int q = atomicAdd(&s_cnt, 1); if (q < CAPC) s_idx[q] = e + 2; }
                if (a.w != 0.0f) { int q = atomicAdd(&s_cnt, 1); if (q < CAPC) s_idx[q] = e + 3; }
            }
        }
        __syncthreads();

        const int c = min(s_cnt, CAPC);
        if (t == 0) g_cnt[b] = c;
        if (t < c)  g_idx[(size_t)b * CAPC + t] = s_idx[t];
    } else {
        // ---- transpose one 64x64 tile of ft_w ----
        const int tb = b - SCAN_BLOCKS;           // 0..2559
        const int f0 = (tb % (NF / 64)) * 64;
        const int m0 = (tb / (NF / 64)) * 64;
        const int tx = t & 63;                    // 0..63
        const int ty = t >> 6;                    // 0..3
        #pragma unroll
        for (int r = ty; r < 64; r += 4)
            tile[r][tx] = ft_w[(size_t)(m0 + r) * NF + f0 + tx];
        __syncthreads();
        #pragma unroll
        for (int r = ty; r < 64; r += 4)
            ftT[(size_t)(f0 + r) * MD + m0 + tx] = tile[tx][r];
    }
}

// ---------------------------------------------------------------------------
// Kernel 2: per-position gather of active ft rows + MLP tail.
// ---------------------------------------------------------------------------
__global__ __launch_bounds__(256) void gather_mlp(
    const float* __restrict__ stm, const float* __restrict__ ftT,
    const int* __restrict__ g_cnt, const int* __restrict__ g_idx,
    const float* __restrict__ ft_b,
    const float* __restrict__ l1_w, const float* __restrict__ l1_b,
    const float* __restrict__ l2_w, const float* __restrict__ l2_b,
    const float* __restrict__ l3_w, const float* __restrict__ l3_b,
    float* __restrict__ out)
{
    __shared__ int lw[NCHUNK * CAPC], lb[NCHUNK * CAPC];
    __shared__ int cnts[8], offs[8];
    __shared__ int cw_s, cb_s;
    __shared__ float xsh[512];
    __shared__ float red[32][9];
    __shared__ float ysh[32], zsh[32];

    const int pos = blockIdx.x;
    const int t = threadIdx.x;

    // counts: cid = (pos*2 + color)*4 + chunk
    if (t < 8) cnts[t] = g_cnt[(pos * 2 + (t >> 2)) * 4 + (t & 3)];
    __syncthreads();
    if (t == 0) {
        int ow = 0, ob = 0;
        #pragma unroll
        for (int c = 0; c < 4; ++c) {
            offs[c]     = ow; ow += cnts[c];
            offs[4 + c] = ob; ob += cnts[4 + c];
        }
        cw_s = ow; cb_s = ob;
    }
    __syncthreads();
    #pragma unroll
    for (int c = 0; c < 4; ++c) {
        if (t < cnts[c])     lw[offs[c] + t]     = g_idx[(size_t)((pos * 2 + 0) * 4 + c) * CAPC + t];
        if (t < cnts[4 + c]) lb[offs[4 + c] + t] = g_idx[(size_t)((pos * 2 + 1) * 4 + c) * CAPC + t];
    }
    __syncthreads();

    const int cw = cw_s, cb = cb_s;

    // thread t owns accumulator channel m = t; ftT row read = 256B/wave contiguous
    float accW = ft_b[t];
    float accB = ft_b[t];
    {
        int j = 0;
        for (; j + 4 <= cw; j += 4) {
            float a0 = ftT[(size_t)lw[j]     * MD + t];
            float a1 = ftT[(size_t)lw[j + 1] * MD + t];
            float a2 = ftT[(size_t)lw[j + 2] * MD + t];
            float a3 = ftT[(size_t)lw[j + 3] * MD + t];
            accW += a0 + a1 + a2 + a3;
        }
        for (; j < cw; ++j) accW += ftT[(size_t)lw[j] * MD + t];
        j = 0;
        for (; j + 4 <= cb; j += 4) {
            float a0 = ftT[(size_t)lb[j]     * MD + t];
            float a1 = ftT[(size_t)lb[j + 1] * MD + t];
            float a2 = ftT[(size_t)lb[j + 2] * MD + t];
            float a3 = ftT[(size_t)lb[j + 3] * MD + t];
            accB += a0 + a1 + a2 + a3;
        }
        for (; j < cb; ++j) accB += ftT[(size_t)lb[j] * MD + t];
    }

    // stm perspective select + clip -> x[512]
    const float s = stm[pos];
    xsh[t]       = clip01(s * accW + (1.0f - s) * accB);
    xsh[256 + t] = clip01(s * accB + (1.0f - s) * accW);
    __syncthreads();

    // L1: y[n] = clip(sum_512 x[j]*l1_w[n][j] + b)
    {
        const int n = t & 31;
        const int c = t >> 5;
        const float* w1 = l1_w + (size_t)n * 512 + c * 64;
        const float* xx = xsh + c * 64;
        float p = 0.0f;
        #pragma unroll
        for (int j = 0; j < 64; ++j) p += xx[j] * w1[j];
        red[n][c] = p;
    }
    __syncthreads();
    if (t < 32) {
        float v = l1_b[t];
        #pragma unroll
        for (int c = 0; c < 8; ++c) v += red[t][c];
        ysh[t] = clip01(v);
    }
    __syncthreads();

    // L2
    if (t < 32) {
        float v = l2_b[t];
        const float* w2 = l2_w + t * 32;
        #pragma unroll
        for (int j = 0; j < 32; ++j) v += ysh[j] * w2[j];
        zsh[t] = clip01(v);
    }
    __syncthreads();

    // L3 + output map
    if (t == 0) {
        float v = l3_b[0];
        #pragma unroll
        for (int j = 0; j < 32; ++j) v += zsh[j] * l3_w[j];
        v = clip01(v);
        out[pos] = (v - 0.5f) * 20000.0f;
    }
}

extern "C" void kernel_launch(void* const* d_in, const int* in_sizes, int n_in,
                              void* d_out, int out_size, void* d_ws, size_t ws_size,
                              hipStream_t stream) {
    const float* wf    = (const float*)d_in[0];
    const float* bfeat = (const float*)d_in[1];
    const float* stm   = (const float*)d_in[2];
    const float* ft_w  = (const float*)d_in[3];
    const float* ft_b  = (const float*)d_in[4];
    const float* l1_w  = (const float*)d_in[5];
    const float* l1_b  = (const float*)d_in[6];
    const float* l2_w  = (const float*)d_in[7];
    const float* l2_b  = (const float*)d_in[8];
    const float* l3_w  = (const float*)d_in[9];
    const float* l3_b  = (const float*)d_in[10];
    float* out = (float*)d_out;

    // ws layout: ftT | counts | indices   (~44.1 MB total; observed ws ~1.3 GB)
    float* ftT   = (float*)d_ws;
    int*   g_cnt = (int*)((char*)d_ws + (size_t)NF * MD * sizeof(float));
    int*   g_idx = g_cnt + SCAN_BLOCKS;

    scan_transpose<<<SCAN_BLOCKS + TRANS_BLOCKS, 256, 0, stream>>>(
        wf, bfeat, ft_w, ftT, g_cnt, g_idx);

    gather_mlp<<<BATCH, 256, 0, stream>>>(
        stm, ftT, g_cnt, g_idx, ft_b,
        l1_w, l1_b, l2_w, l2_b, l3_w, l3_b, out);
}